// Round 1
// baseline (93.711 us; speedup 1.0000x reference)
//
#include <hip/hip_runtime.h>
#include <hip/hip_bf16.h>

typedef __attribute__((ext_vector_type(4))) float f32x4;
typedef __attribute__((ext_vector_type(8))) short short8;
typedef __attribute__((ext_vector_type(8))) unsigned short ushort8;

#define NB 8
#define NN 2048
#define NF 128
#define LRELU_ALPHA 0.2f
#define NEG_INF_F -9000000000000000.0f

static __device__ __forceinline__ unsigned short f2bf(float f) {
    unsigned int u = __float_as_uint(f);
    u += 0x7fffu + ((u >> 16) & 1u);
    return (unsigned short)(u >> 16);
}

// Kernel A: h_prime = h @ W (fp32), si = hp@a1, sj = hp@a2, and hpT (bf16, [b][f][n])
__global__ __launch_bounds__(256) void k_hprime(
    const float* __restrict__ h, const float* __restrict__ W,
    const float* __restrict__ a, unsigned short* __restrict__ hpT,
    float* __restrict__ si, float* __restrict__ sj)
{
    __shared__ float Wsh[NF * NF];  // 64 KiB
    const int t = threadIdx.x;
    const int blk = blockIdx.x;
    const int b = blk >> 6;                       // 64 row-blocks per batch
    const int row = ((blk & 63) << 5) + (t >> 3); // 32 rows per block, 8 thr/row
    const int l8 = t & 7;

    const f32x4* W4 = reinterpret_cast<const f32x4*>(W);
    f32x4* Wsh4 = reinterpret_cast<f32x4*>(Wsh);
    #pragma unroll
    for (int u = 0; u < 16; ++u) Wsh4[u * 256 + t] = W4[u * 256 + t];
    __syncthreads();

    float acc[16];
    #pragma unroll
    for (int i = 0; i < 16; ++i) acc[i] = 0.f;

    // thread owns cols: q*32 + l8*4 + cc  (conflict-free LDS banks)
    const float* hrow = h + (size_t)(b * NN + row) * NF;
    for (int k0 = 0; k0 < NF; k0 += 8) {
        f32x4 h0 = *reinterpret_cast<const f32x4*>(hrow + k0);
        f32x4 h1 = *reinterpret_cast<const f32x4*>(hrow + k0 + 4);
        #pragma unroll
        for (int kk = 0; kk < 8; ++kk) {
            float hv = (kk < 4) ? h0[kk] : h1[kk - 4];
            const float* wr = &Wsh[(k0 + kk) * NF + l8 * 4];
            #pragma unroll
            for (int q = 0; q < 4; ++q) {
                f32x4 wv = *reinterpret_cast<const f32x4*>(wr + q * 32);
                acc[q*4+0] += hv * wv[0];
                acc[q*4+1] += hv * wv[1];
                acc[q*4+2] += hv * wv[2];
                acc[q*4+3] += hv * wv[3];
            }
        }
    }

    float s1 = 0.f, s2 = 0.f;
    #pragma unroll
    for (int q = 0; q < 4; ++q) {
        #pragma unroll
        for (int cc = 0; cc < 4; ++cc) {
            int col = q * 32 + l8 * 4 + cc;
            s1 += acc[q*4+cc] * a[col];
            s2 += acc[q*4+cc] * a[NF + col];
        }
    }
    s1 += __shfl_xor(s1, 1); s1 += __shfl_xor(s1, 2); s1 += __shfl_xor(s1, 4);
    s2 += __shfl_xor(s2, 1); s2 += __shfl_xor(s2, 2); s2 += __shfl_xor(s2, 4);
    if (l8 == 0) {
        si[b * NN + row] = s1;
        sj[b * NN + row] = s2;
    }
    #pragma unroll
    for (int q = 0; q < 4; ++q) {
        #pragma unroll
        for (int cc = 0; cc < 4; ++cc) {
            int col = q * 32 + l8 * 4 + cc;
            hpT[(size_t)(b * NF + col) * NN + row] = f2bf(acc[q*4+cc]);
        }
    }
}

// Kernel B: bias[i][j] = adj>0 ? -log(dist+1e-6)*scale : NEG_INF
__global__ __launch_bounds__(256) void k_bias(
    const int* __restrict__ adj, const float* __restrict__ dist,
    const float* __restrict__ scaler, float* __restrict__ bias)
{
    const int idx = (blockIdx.x * 256 + threadIdx.x) * 4;
    const float sc = scaler[0];
    int4 av = *reinterpret_cast<const int4*>(adj + idx);
    float4 dv = *reinterpret_cast<const float4*>(dist + idx);
    float4 ov;
    ov.x = (av.x > 0) ? (-__logf(dv.x + 1e-6f) * sc) : NEG_INF_F;
    ov.y = (av.y > 0) ? (-__logf(dv.y + 1e-6f) * sc) : NEG_INF_F;
    ov.z = (av.z > 0) ? (-__logf(dv.z + 1e-6f) * sc) : NEG_INF_F;
    ov.w = (av.w > 0) ? (-__logf(dv.w + 1e-6f) * sc) : NEG_INF_F;
    *reinterpret_cast<float4*>(bias + idx) = ov;
}

// Kernel C: flash-style masked-bias softmax + PV (bf16 MFMA) + elu
// Block: 256 thr = 4 waves, BI=32 i-rows, loop j-tiles of BJ=64.
// Wave w owns output cols [w*32, w*32+32), all 32 rows.
__global__ __launch_bounds__(256) void k_attn(
    const unsigned short* __restrict__ hpT, const float* __restrict__ si,
    const float* __restrict__ sj, const float* __restrict__ bias,
    float* __restrict__ out)
{
    __shared__ __align__(16) unsigned short sP[32][72]; // P tile bf16, padded stride
    __shared__ float sM[32], sL[32], sR[32];

    const int t = threadIdx.x;
    const int blk = blockIdx.x;
    const int b = blk >> 6;
    const int i0 = (blk & 63) << 5;
    const int row = t >> 3;        // 0..31
    const int jc = (t & 7) << 3;   // 8 score cols per thread
    const int lane = t & 63;
    const int w = t >> 6;

    if (t < 32) { sM[t] = -INFINITY; sL[t] = 0.f; }

    f32x4 acc[2][2];
    #pragma unroll
    for (int mt = 0; mt < 2; ++mt)
        #pragma unroll
        for (int nt = 0; nt < 2; ++nt)
            #pragma unroll
            for (int e = 0; e < 4; ++e) acc[mt][nt][e] = 0.f;

    const float siv = si[b * NN + i0 + row];
    const float* sjb = sj + b * NN;
    const float* biasrow = bias + (size_t)(i0 + row) * NN;
    __syncthreads();

    for (int j0 = 0; j0 < NN; j0 += 64) {
        // ---- score phase: s = lrelu(si+sj) + bias, online softmax ----
        f32x4 b0 = *reinterpret_cast<const f32x4*>(biasrow + j0 + jc);
        f32x4 b1 = *reinterpret_cast<const f32x4*>(biasrow + j0 + jc + 4);
        f32x4 sj0 = *reinterpret_cast<const f32x4*>(sjb + j0 + jc);
        f32x4 sj1 = *reinterpret_cast<const f32x4*>(sjb + j0 + jc + 4);
        float s[8];
        #pragma unroll
        for (int u = 0; u < 8; ++u) {
            float e = siv + ((u < 4) ? sj0[u] : sj1[u - 4]);
            e = (e >= 0.f) ? e : (LRELU_ALPHA * e);
            s[u] = e + ((u < 4) ? b0[u] : b1[u - 4]);
        }
        float mx = s[0];
        #pragma unroll
        for (int u = 1; u < 8; ++u) mx = fmaxf(mx, s[u]);
        mx = fmaxf(mx, __shfl_xor(mx, 1));
        mx = fmaxf(mx, __shfl_xor(mx, 2));
        mx = fmaxf(mx, __shfl_xor(mx, 4));
        const float m_old = sM[row];
        const float m_new = fmaxf(m_old, mx);
        const float r = __expf(m_old - m_new);
        float ps = 0.f;
        ushort8 pv;
        #pragma unroll
        for (int u = 0; u < 8; ++u) {
            float p = __expf(s[u] - m_new);
            ps += p;
            pv[u] = f2bf(p);
        }
        ps += __shfl_xor(ps, 1); ps += __shfl_xor(ps, 2); ps += __shfl_xor(ps, 4);
        *reinterpret_cast<ushort8*>(&sP[row][jc]) = pv;
        if ((t & 7) == 0) {
            sL[row] = sL[row] * r + ps;
            sM[row] = m_new;
            sR[row] = r;
        }
        __syncthreads();

        // ---- rescale + MFMA phase ----
        #pragma unroll
        for (int mt = 0; mt < 2; ++mt) {
            #pragma unroll
            for (int e = 0; e < 4; ++e) {
                float f = sR[mt * 16 + ((lane >> 4) << 2) + e];
                acc[mt][0][e] *= f;
                acc[mt][1][e] *= f;
            }
        }
        short8 afr[2][2];
        #pragma unroll
        for (int mt = 0; mt < 2; ++mt)
            #pragma unroll
            for (int k = 0; k < 2; ++k)
                afr[mt][k] = *reinterpret_cast<short8*>(
                    &sP[mt * 16 + (lane & 15)][k * 32 + ((lane >> 4) << 3)]);
        #pragma unroll
        for (int k = 0; k < 2; ++k) {
            #pragma unroll
            for (int nt = 0; nt < 2; ++nt) {
                int col = (w << 5) + nt * 16 + (lane & 15);
                short8 bfr = *reinterpret_cast<const short8*>(
                    hpT + (size_t)(b * NF + col) * NN + j0 + k * 32 + ((lane >> 4) << 3));
                acc[0][nt] = __builtin_amdgcn_mfma_f32_16x16x32_bf16(afr[0][k], bfr, acc[0][nt], 0, 0, 0);
                acc[1][nt] = __builtin_amdgcn_mfma_f32_16x16x32_bf16(afr[1][k], bfr, acc[1][nt], 0, 0, 0);
            }
        }
        __syncthreads();
    }

    // ---- epilogue: out = elu(O / l) ----
    #pragma unroll
    for (int mt = 0; mt < 2; ++mt) {
        #pragma unroll
        for (int nt = 0; nt < 2; ++nt) {
            #pragma unroll
            for (int e = 0; e < 4; ++e) {
                int rr = mt * 16 + ((lane >> 4) << 2) + e;
                float v = acc[mt][nt][e] / sL[rr];
                v = (v > 0.f) ? v : expm1f(v);
                out[(size_t)(b * NN + i0 + rr) * NF + (w << 5) + nt * 16 + (lane & 15)] = v;
            }
        }
    }
}

extern "C" void kernel_launch(void* const* d_in, const int* in_sizes, int n_in,
                              void* d_out, int out_size, void* d_ws, size_t ws_size,
                              hipStream_t stream) {
    (void)in_sizes; (void)n_in; (void)out_size; (void)ws_size;
    const float* h      = (const float*)d_in[0];
    const int*   adj    = (const int*)d_in[1];
    const float* dist   = (const float*)d_in[2];
    const float* W      = (const float*)d_in[3];
    const float* a      = (const float*)d_in[4];
    const float* scaler = (const float*)d_in[5];
    float* out = (float*)d_out;

    char* ws = (char*)d_ws;
    unsigned short* hpT = (unsigned short*)ws;                 // 4 MiB  (8*128*2048 bf16)
    float* si   = (float*)(ws + 4 * 1024 * 1024);              // 64 KiB
    float* sj   = (float*)(ws + 4 * 1024 * 1024 + 65536);      // 64 KiB
    float* bias = (float*)(ws + 4 * 1024 * 1024 + 2 * 65536);  // 16 MiB

    k_hprime<<<dim3(NB * NN / 32), dim3(256), 0, stream>>>(h, W, a, hpT, si, sj);
    k_bias<<<dim3(NN * NN / 1024), dim3(256), 0, stream>>>(adj, dist, scaler, bias);
    k_attn<<<dim3(NB * NN / 32), dim3(256), 0, stream>>>(hpT, si, sj, bias, out);
}

// Round 2
// 79.193 us; speedup vs baseline: 1.1833x; 1.1833x over previous
//
#include <hip/hip_runtime.h>
#include <hip/hip_bf16.h>

typedef __attribute__((ext_vector_type(4))) float f32x4;
typedef __attribute__((ext_vector_type(8))) short short8;
typedef __attribute__((ext_vector_type(4))) unsigned short ushort4v;

#define NB 8
#define NN 2048
#define NF 128
#define LOG2E 1.4426950408889634f
#define MASK_NEG -1.0e30f

static __device__ __forceinline__ unsigned short f2bf(float f) {
    union { __hip_bfloat16 b; unsigned short u; } cv;
    cv.b = __float2bfloat16(f);
    return cv.u;
}

// ---------------------------------------------------------------------------
// Kernel A: h_prime = h @ W via bf16 MFMA -> hpT (bf16, [b][f][n]);
// siC/sjC = (h @ (W@a1,2)) * log2e  in fp32 (exact GEMV, fused).
// Self-contained: stages W^T bf16 (swizzled) + Wa vectors per block.
// ---------------------------------------------------------------------------
__global__ __launch_bounds__(256) void k_hprime(
    const float* __restrict__ h, const float* __restrict__ W,
    const float* __restrict__ a, unsigned short* __restrict__ hpT,
    float* __restrict__ siC, float* __restrict__ sjC)
{
    __shared__ __align__(16) unsigned char WT[32768];  // W^T bf16, swizzled [col][f]
    __shared__ float wa1[NF], wa2[NF];

    const int t = threadIdx.x;
    const int lane = t & 63;
    const int w = t >> 6;                 // 4 waves
    const int b = blockIdx.x >> 5;
    const int i0 = (blockIdx.x & 31) << 6;

    // ---- stage W^T + compute Wa vectors (once per block) ----
    {
        const int f = t >> 1;             // 0..127
        const int c0 = (t & 1) << 6;      // 0 or 64
        float s1 = 0.f, s2 = 0.f;
        const float* wrow = W + f * NF + c0;
        const float* a1p = a + c0;
        const float* a2p = a + NF + c0;
        #pragma unroll 8
        for (int c = 0; c < 64; ++c) {
            float wv = wrow[c];
            s1 += wv * a1p[c];
            s2 += wv * a2p[c];
            int col = c0 + c;
            int dst = col * 256 + ((2 * f) ^ ((col & 15) << 4));
            *reinterpret_cast<unsigned short*>(&WT[dst]) = f2bf(wv);
        }
        s1 += __shfl_xor(s1, 1);
        s2 += __shfl_xor(s2, 1);
        if ((t & 1) == 0) { wa1[f] = s1 * LOG2E; wa2[f] = s2 * LOG2E; }
    }
    __syncthreads();

    const int arow = i0 + w * 16 + (lane & 15);
    const int kofs = (lane >> 4) << 3;    // 0,8,16,24
    const float* hrow = h + (size_t)(b * NN + arow) * NF + kofs;
    const int swz = (lane & 15) << 4;

    f32x4 acc[8];
    #pragma unroll
    for (int nt = 0; nt < 8; ++nt) acc[nt] = (f32x4)(0.f);
    float s1 = 0.f, s2 = 0.f;

    #pragma unroll
    for (int k0 = 0; k0 < NF; k0 += 32) {
        f32x4 h0 = *reinterpret_cast<const f32x4*>(hrow + k0);
        f32x4 h1 = *reinterpret_cast<const f32x4*>(hrow + k0 + 4);
        f32x4 w1lo = *reinterpret_cast<const f32x4*>(&wa1[k0 + kofs]);
        f32x4 w1hi = *reinterpret_cast<const f32x4*>(&wa1[k0 + kofs + 4]);
        f32x4 w2lo = *reinterpret_cast<const f32x4*>(&wa2[k0 + kofs]);
        f32x4 w2hi = *reinterpret_cast<const f32x4*>(&wa2[k0 + kofs + 4]);
        short8 af;
        #pragma unroll
        for (int e = 0; e < 4; ++e) {
            s1 += h0[e] * w1lo[e] + h1[e] * w1hi[e];
            s2 += h0[e] * w2lo[e] + h1[e] * w2hi[e];
            af[e]     = (short)f2bf(h0[e]);
            af[4 + e] = (short)f2bf(h1[e]);
        }
        const int ib = (2 * (k0 + kofs)) ^ swz;
        #pragma unroll
        for (int nt = 0; nt < 8; ++nt) {
            short8 bf8 = *reinterpret_cast<short8*>(&WT[(nt * 16 + (lane & 15)) * 256 + ib]);
            acc[nt] = __builtin_amdgcn_mfma_f32_16x16x32_bf16(af, bf8, acc[nt], 0, 0, 0);
        }
    }

    // si/sj: rows live at lanes l,l+16,l+32,l+48 (same l&15)
    s1 += __shfl_xor(s1, 16); s1 += __shfl_xor(s1, 32);
    s2 += __shfl_xor(s2, 16); s2 += __shfl_xor(s2, 32);
    if (lane < 16) {
        siC[b * NN + arow] = s1;
        sjC[b * NN + arow] = s2;
    }

    // hpT[b][col][i]: C layout col=lane&15, row=(lane>>4)*4+e (consecutive -> 8B store)
    #pragma unroll
    for (int nt = 0; nt < 8; ++nt) {
        int col = nt * 16 + (lane & 15);
        ushort4v pk;
        #pragma unroll
        for (int e = 0; e < 4; ++e) pk[e] = f2bf(acc[nt][e]);
        *reinterpret_cast<ushort4v*>(
            hpT + (size_t)(b * NF + col) * NN + i0 + w * 16 + ((lane >> 4) << 2)) = pk;
    }
}

// ---------------------------------------------------------------------------
// Kernel B: biasC[i][j] = adj>0 ? -log2(dist+1e-6)*scale : -1e30
// (log2e folded: -ln(d)*sc*log2e == -log2(d)*sc)
// ---------------------------------------------------------------------------
__global__ __launch_bounds__(256) void k_bias(
    const int* __restrict__ adj, const float* __restrict__ dist,
    const float* __restrict__ scaler, float* __restrict__ biasC)
{
    const int idx = (blockIdx.x * 256 + threadIdx.x) * 4;
    const float sc = scaler[0];
    int4 av = *reinterpret_cast<const int4*>(adj + idx);
    float4 dv = *reinterpret_cast<const float4*>(dist + idx);
    float4 ov;
    ov.x = (av.x > 0) ? (-__log2f(dv.x + 1e-6f) * sc) : MASK_NEG;
    ov.y = (av.y > 0) ? (-__log2f(dv.y + 1e-6f) * sc) : MASK_NEG;
    ov.z = (av.z > 0) ? (-__log2f(dv.z + 1e-6f) * sc) : MASK_NEG;
    ov.w = (av.w > 0) ? (-__log2f(dv.w + 1e-6f) * sc) : MASK_NEG;
    *reinterpret_cast<float4*>(biasC + idx) = ov;
}

// ---------------------------------------------------------------------------
// Kernel C: static-max softmax + PV.  512 thr = 8 waves; block = 64 i-rows,
// wave = 16 rows x 64 cols (col-half ch, row-tile r). j-tiles of 128 staged
// in LDS (swizzled, double-buffered, 1 barrier/tile). P is lane-local.
// ---------------------------------------------------------------------------
__global__ __launch_bounds__(512) void k_attn(
    const unsigned short* __restrict__ hpT, const float* __restrict__ siC,
    const float* __restrict__ sjC, const float* __restrict__ biasC,
    float* __restrict__ out)
{
    __shared__ __align__(16) unsigned char tile[2][32768];  // [128 cols][128 j] bf16, swizzled

    const int t = threadIdx.x;
    const int lane = t & 63;
    const int w = t >> 6;       // 0..7
    const int r = w & 3;        // row-tile
    const int ch = w >> 2;      // col-half

    // XCD swizzle: each XCD keeps one 256-row bias slice L2-resident across 8 batches
    const int bid2 = (blockIdx.x & 7) * 32 + (blockIdx.x >> 3);
    const int b = bid2 & 7;
    const int i0 = (bid2 >> 3) << 6;

    const int irow = i0 + r * 16 + (lane & 15);
    const float si_r = siC[b * NN + irow];
    const int jofs = (lane >> 4) << 3;  // 0,8,16,24
    const float* brow = biasC + (size_t)irow * NN + jofs;
    const float* sjrow = sjC + b * NN + jofs;

    // staging: 4 chunks of 16B per thread per 128-j tile
    const unsigned short* gsrc[4];
    int gdst[4];
    #pragma unroll
    for (int u = 0; u < 4; ++u) {
        int c = t + u * 512;            // chunk id 0..2047
        int col = c >> 4;               // 0..127
        int jj0 = (c & 15) << 3;        // 0..120
        gsrc[u] = hpT + (size_t)(b * NF + col) * NN + jj0;
        gdst[u] = col * 256 + ((jj0 * 2) ^ ((col & 15) << 4));
    }

    // prologue: stage tile 0
    #pragma unroll
    for (int u = 0; u < 4; ++u)
        *reinterpret_cast<short8*>(&tile[0][gdst[u]]) =
            *reinterpret_cast<const short8*>(gsrc[u]);
    __syncthreads();

    f32x4 acc[4];
    #pragma unroll
    for (int nt = 0; nt < 4; ++nt) acc[nt] = (f32x4)(0.f);
    float lsum = 0.f;

    const int colb = (ch * 64 + (lane & 15)) * 256;
    const int swz = (lane & 15) << 4;

    for (int jt = 0; jt < 16; ++jt) {
        const int cur = jt & 1;
        // issue next-tile global loads early (hide under compute)
        short8 v[4];
        if (jt + 1 < 16) {
            #pragma unroll
            for (int u = 0; u < 4; ++u)
                v[u] = *reinterpret_cast<const short8*>(gsrc[u] + (jt + 1) * 128);
        }
        #pragma unroll
        for (int kk = 0; kk < 4; ++kk) {
            const int j = jt * 128 + kk * 32;
            f32x4 b0 = *reinterpret_cast<const f32x4*>(brow + j);
            f32x4 b1 = *reinterpret_cast<const f32x4*>(brow + j + 4);
            f32x4 s0 = *reinterpret_cast<const f32x4*>(sjrow + j);
            f32x4 s1 = *reinterpret_cast<const f32x4*>(sjrow + j + 4);
            short8 pa;
            #pragma unroll
            for (int e = 0; e < 8; ++e) {
                float x = si_r + ((e < 4) ? s0[e] : s1[e - 4]);
                float y = fmaxf(x, 0.2f * x) + ((e < 4) ? b0[e] : b1[e - 4]);
                float p = __builtin_amdgcn_exp2f(y);
                lsum += p;
                pa[e] = (short)f2bf(p);
            }
            const int inner = (((kk << 6) | ((lane >> 4) << 4)) ^ swz) + cur * 32768;
            #pragma unroll
            for (int nt = 0; nt < 4; ++nt) {
                const short8 pb = *reinterpret_cast<const short8*>(
                    &tile[0][colb + nt * 4096 + inner]);
                acc[nt] = __builtin_amdgcn_mfma_f32_16x16x32_bf16(pa, pb, acc[nt], 0, 0, 0);
            }
        }
        if (jt + 1 < 16) {
            #pragma unroll
            for (int u = 0; u < 4; ++u)
                *reinterpret_cast<short8*>(&tile[cur ^ 1][gdst[u]]) = v[u];
        }
        __syncthreads();
    }

    // row-sum l: lanes l,l+16,l+32,l+48 hold partials of row (l&15)
    lsum += __shfl_xor(lsum, 16);
    lsum += __shfl_xor(lsum, 32);
    float linv[4];
    #pragma unroll
    for (int e = 0; e < 4; ++e)
        linv[e] = 1.0f / __shfl(lsum, ((lane >> 4) << 2) + e);

    #pragma unroll
    for (int nt = 0; nt < 4; ++nt) {
        #pragma unroll
        for (int e = 0; e < 4; ++e) {
            int rr = i0 + r * 16 + ((lane >> 4) << 2) + e;
            float vv = acc[nt][e] * linv[e];
            vv = (vv > 0.f) ? vv : expm1f(vv);
            out[(size_t)(b * NN + rr) * NF + ch * 64 + nt * 16 + (lane & 15)] = vv;
        }
    }
}

extern "C" void kernel_launch(void* const* d_in, const int* in_sizes, int n_in,
                              void* d_out, int out_size, void* d_ws, size_t ws_size,
                              hipStream_t stream) {
    (void)in_sizes; (void)n_in; (void)out_size; (void)ws_size;
    const float* h      = (const float*)d_in[0];
    const int*   adj    = (const int*)d_in[1];
    const float* dist   = (const float*)d_in[2];
    const float* W      = (const float*)d_in[3];
    const float* a      = (const float*)d_in[4];
    const float* scaler = (const float*)d_in[5];
    float* out = (float*)d_out;

    char* ws = (char*)d_ws;
    unsigned short* hpT = (unsigned short*)ws;                 // 4 MiB
    float* siC   = (float*)(ws + 4 * 1024 * 1024);             // 64 KiB
    float* sjC   = (float*)(ws + 4 * 1024 * 1024 + 65536);     // 64 KiB
    float* biasC = (float*)(ws + 4 * 1024 * 1024 + 2 * 65536); // 16 MiB

    k_hprime<<<dim3(NB * NN / 64), dim3(256), 0, stream>>>(h, W, a, hpT, siC, sjC);
    k_bias<<<dim3(NN * NN / 1024), dim3(256), 0, stream>>>(adj, dist, scaler, biasC);
    k_attn<<<dim3(NB * NN / 64), dim3(512), 0, stream>>>(hpT, siC, sjC, biasC, out);
}

// Round 3
// 67.381 us; speedup vs baseline: 1.3908x; 1.1753x over previous
//
#include <hip/hip_runtime.h>
#include <hip/hip_bf16.h>

typedef __attribute__((ext_vector_type(4))) float f32x4;
typedef __attribute__((ext_vector_type(8))) short short8;
typedef __attribute__((ext_vector_type(4))) unsigned short ushort4v;

#define NB 8
#define NN 2048
#define NF 128
#define LOG2E 1.4426950408889634f
#define MASK_NEG -1.0e30f

static __device__ __forceinline__ unsigned short f2bf(float f) {
    union { __hip_bfloat16 b; unsigned short u; } cv;
    cv.b = __float2bfloat16(f);
    return cv.u;
}

// ---------------------------------------------------------------------------
// Kernel A: h_prime = h @ W via bf16 MFMA -> hpT (bf16, [b][f][n]);
// siC/sjC = (h @ (W@a1,2)) * log2e in fp32 (exact GEMV, fused).
// ---------------------------------------------------------------------------
__global__ __launch_bounds__(256) void k_hprime(
    const float* __restrict__ h, const float* __restrict__ W,
    const float* __restrict__ a, unsigned short* __restrict__ hpT,
    float* __restrict__ siC, float* __restrict__ sjC)
{
    __shared__ __align__(16) unsigned char WT[32768];  // W^T bf16, swizzled [col][f]
    __shared__ float wa1[NF], wa2[NF];

    const int t = threadIdx.x;
    const int lane = t & 63;
    const int w = t >> 6;                 // 4 waves
    const int b = blockIdx.x >> 5;
    const int i0 = (blockIdx.x & 31) << 6;

    {
        const int f = t >> 1;             // 0..127
        const int c0 = (t & 1) << 6;      // 0 or 64
        float s1 = 0.f, s2 = 0.f;
        const float* wrow = W + f * NF + c0;
        const float* a1p = a + c0;
        const float* a2p = a + NF + c0;
        #pragma unroll 8
        for (int c = 0; c < 64; ++c) {
            float wv = wrow[c];
            s1 += wv * a1p[c];
            s2 += wv * a2p[c];
            int col = c0 + c;
            int dst = col * 256 + ((2 * f) ^ ((col & 15) << 4));
            *reinterpret_cast<unsigned short*>(&WT[dst]) = f2bf(wv);
        }
        s1 += __shfl_xor(s1, 1);
        s2 += __shfl_xor(s2, 1);
        if ((t & 1) == 0) { wa1[f] = s1 * LOG2E; wa2[f] = s2 * LOG2E; }
    }
    __syncthreads();

    const int arow = i0 + w * 16 + (lane & 15);
    const int kofs = (lane >> 4) << 3;    // 0,8,16,24
    const float* hrow = h + (size_t)(b * NN + arow) * NF + kofs;
    const int swz = (lane & 15) << 4;

    f32x4 acc[8];
    #pragma unroll
    for (int nt = 0; nt < 8; ++nt) acc[nt] = (f32x4)(0.f);
    float s1 = 0.f, s2 = 0.f;

    #pragma unroll
    for (int k0 = 0; k0 < NF; k0 += 32) {
        f32x4 h0 = *reinterpret_cast<const f32x4*>(hrow + k0);
        f32x4 h1 = *reinterpret_cast<const f32x4*>(hrow + k0 + 4);
        f32x4 w1lo = *reinterpret_cast<const f32x4*>(&wa1[k0 + kofs]);
        f32x4 w1hi = *reinterpret_cast<const f32x4*>(&wa1[k0 + kofs + 4]);
        f32x4 w2lo = *reinterpret_cast<const f32x4*>(&wa2[k0 + kofs]);
        f32x4 w2hi = *reinterpret_cast<const f32x4*>(&wa2[k0 + kofs + 4]);
        short8 af;
        #pragma unroll
        for (int e = 0; e < 4; ++e) {
            s1 += h0[e] * w1lo[e] + h1[e] * w1hi[e];
            s2 += h0[e] * w2lo[e] + h1[e] * w2hi[e];
            af[e]     = (short)f2bf(h0[e]);
            af[4 + e] = (short)f2bf(h1[e]);
        }
        const int ib = (2 * (k0 + kofs)) ^ swz;
        #pragma unroll
        for (int nt = 0; nt < 8; ++nt) {
            short8 bf8 = *reinterpret_cast<short8*>(&WT[(nt * 16 + (lane & 15)) * 256 + ib]);
            acc[nt] = __builtin_amdgcn_mfma_f32_16x16x32_bf16(af, bf8, acc[nt], 0, 0, 0);
        }
    }

    s1 += __shfl_xor(s1, 16); s1 += __shfl_xor(s1, 32);
    s2 += __shfl_xor(s2, 16); s2 += __shfl_xor(s2, 32);
    if (lane < 16) {
        siC[b * NN + arow] = s1;
        sjC[b * NN + arow] = s2;
    }

    #pragma unroll
    for (int nt = 0; nt < 8; ++nt) {
        int col = nt * 16 + (lane & 15);
        ushort4v pk;
        #pragma unroll
        for (int e = 0; e < 4; ++e) pk[e] = f2bf(acc[nt][e]);
        *reinterpret_cast<ushort4v*>(
            hpT + (size_t)(b * NF + col) * NN + i0 + w * 16 + ((lane >> 4) << 2)) = pk;
    }
}

// ---------------------------------------------------------------------------
// Kernel B: biasC[i][j] = adj>0 ? -log2(dist+1e-6)*scale : -1e30
// ---------------------------------------------------------------------------
__global__ __launch_bounds__(256) void k_bias(
    const int* __restrict__ adj, const float* __restrict__ dist,
    const float* __restrict__ scaler, float* __restrict__ biasC)
{
    const int idx = (blockIdx.x * 256 + threadIdx.x) * 4;
    const float sc = scaler[0];
    int4 av = *reinterpret_cast<const int4*>(adj + idx);
    float4 dv = *reinterpret_cast<const float4*>(dist + idx);
    float4 ov;
    ov.x = (av.x > 0) ? (-__log2f(dv.x + 1e-6f) * sc) : MASK_NEG;
    ov.y = (av.y > 0) ? (-__log2f(dv.y + 1e-6f) * sc) : MASK_NEG;
    ov.z = (av.z > 0) ? (-__log2f(dv.z + 1e-6f) * sc) : MASK_NEG;
    ov.w = (av.w > 0) ? (-__log2f(dv.w + 1e-6f) * sc) : MASK_NEG;
    *reinterpret_cast<float4*>(biasC + idx) = ov;
}

// ---------------------------------------------------------------------------
// Kernel C: static-max softmax + PV, j-split-4 inside the block.
// 512 thr = 8 waves: jh = w>>1 (j-quarter of 512), r = w&1 (16-row tile).
// Block = 32 i-rows; grid 512 (2 blocks/CU -> 16 waves/CU = 4/SIMD).
// 16 rounds x (1 MFMA K-step of 32 j); V tiles 4x8KB double-buffered (64KB).
// Lane-local P (A-frag slots), zero cross-wave softmax state; LDS combine
// of the 4 j-quarter partials at the end.
// ---------------------------------------------------------------------------
__global__ __launch_bounds__(512, 4) void k_attn(
    const unsigned short* __restrict__ hpT, const float* __restrict__ siC,
    const float* __restrict__ sjC, const float* __restrict__ biasC,
    float* __restrict__ out)
{
    __shared__ __align__(16) unsigned char sm[65536];

    const int t = threadIdx.x;
    const int lane = t & 63;
    const int w = t >> 6;        // 0..7
    const int r = w & 1;         // row-tile
    const int jh = w >> 1;       // j-quarter

    // XCD swizzle: XCD x owns row-groups [8x,8x+8) x all 8 batches
    // (bias window 2MB L2-resident; 8 consecutive blocks share batch -> V[b] hot)
    const int bid = blockIdx.x;
    const int kb = bid >> 3;
    const int b = kb >> 3;
    const int rg = (bid & 7) * 8 + (kb & 7);

    const int row16 = lane & 15;
    const int q4 = lane >> 4;    // 0..3
    const int irow = rg * 32 + r * 16 + row16;
    const float si_r = siC[b * NN + irow];
    const float* brow = biasC + (size_t)irow * NN + jh * 512 + q4 * 8;
    const float* sjrow = sjC + b * NN + jh * 512 + q4 * 8;

    // staging: 4 chunks of 16B per thread per round (tile u = j-quarter u)
    const unsigned short* gsrc[4];
    int gdst[4];
    {
        const int col_s = (t >> 2) & 127;
        const int jslot = t & 3;
        #pragma unroll
        for (int u = 0; u < 4; ++u) {
            gsrc[u] = hpT + (size_t)(b * NF + col_s) * NN + u * 512 + jslot * 8;
            gdst[u] = u * 8192 + col_s * 64 + ((jslot << 4) ^ ((col_s & 3) << 4));
        }
    }

    // prologue: stage round 0 into buf0
    #pragma unroll
    for (int u = 0; u < 4; ++u)
        *reinterpret_cast<short8*>(&sm[gdst[u]]) =
            *reinterpret_cast<const short8*>(gsrc[u]);
    __syncthreads();

    f32x4 acc[8];
    #pragma unroll
    for (int nt = 0; nt < 8; ++nt) acc[nt] = (f32x4)(0.f);
    float lsum = 0.f;

    #pragma unroll 2
    for (int round = 0; round < 16; ++round) {
        const int cur = (round & 1) << 15;
        // issue next-round global loads early
        short8 v0, v1, v2, v3;
        if (round < 15) {
            v0 = *reinterpret_cast<const short8*>(gsrc[0] + (round + 1) * 32);
            v1 = *reinterpret_cast<const short8*>(gsrc[1] + (round + 1) * 32);
            v2 = *reinterpret_cast<const short8*>(gsrc[2] + (round + 1) * 32);
            v3 = *reinterpret_cast<const short8*>(gsrc[3] + (round + 1) * 32);
        }
        // scores for this wave's 32-j strip (lane-local A-frag)
        const int jof = round * 32;
        f32x4 b0 = *reinterpret_cast<const f32x4*>(brow + jof);
        f32x4 b1 = *reinterpret_cast<const f32x4*>(brow + jof + 4);
        f32x4 s0 = *reinterpret_cast<const f32x4*>(sjrow + jof);
        f32x4 s1 = *reinterpret_cast<const f32x4*>(sjrow + jof + 4);
        short8 pa;
        #pragma unroll
        for (int e = 0; e < 8; ++e) {
            float x = si_r + ((e < 4) ? s0[e] : s1[e - 4]);
            float y = fmaxf(x, 0.2f * x) + ((e < 4) ? b0[e] : b1[e - 4]);
            float p = __builtin_amdgcn_exp2f(y);
            lsum += p;
            pa[e] = (short)f2bf(p);
        }
        // PV MFMA: 8 col-tiles
        #pragma unroll
        for (int nt = 0; nt < 8; ++nt) {
            const int col = nt * 16 + row16;
            const short8 pb = *reinterpret_cast<const short8*>(
                &sm[cur + jh * 8192 + col * 64 + (((q4 << 4)) ^ ((col & 3) << 4))]);
            acc[nt] = __builtin_amdgcn_mfma_f32_16x16x32_bf16(pa, pb, acc[nt], 0, 0, 0);
        }
        // write next-round tile into other buffer
        if (round < 15) {
            const int nxt = cur ^ 32768;
            *reinterpret_cast<short8*>(&sm[nxt + gdst[0]]) = v0;
            *reinterpret_cast<short8*>(&sm[nxt + gdst[1]]) = v1;
            *reinterpret_cast<short8*>(&sm[nxt + gdst[2]]) = v2;
            *reinterpret_cast<short8*>(&sm[nxt + gdst[3]]) = v3;
        }
        __syncthreads();
    }

    // ---- combine 4 j-quarter partials ----
    lsum += __shfl_xor(lsum, 16);
    lsum += __shfl_xor(lsum, 32);
    float* ltot = (float*)(sm + 49152);   // [6][16]
    if (jh != 0) {
        const int pi = (jh - 1) * 2 + r;
        #pragma unroll
        for (int nt = 0; nt < 8; ++nt) {
            const int col = nt * 16 + row16;
            *reinterpret_cast<f32x4*>(
                &sm[pi * 8192 + col * 64 + ((q4 << 4) ^ ((col & 3) << 4))]) = acc[nt];
        }
        if (lane < 16) ltot[pi * 16 + lane] = lsum;
    }
    __syncthreads();
    if (jh == 0) {
        const float tl = lsum + ltot[(0 * 2 + r) * 16 + row16]
                              + ltot[(1 * 2 + r) * 16 + row16]
                              + ltot[(2 * 2 + r) * 16 + row16];
        float linv[4];
        #pragma unroll
        for (int e = 0; e < 4; ++e)
            linv[e] = 1.0f / __shfl(tl, (q4 << 2) + e);
        #pragma unroll
        for (int nt = 0; nt < 8; ++nt) {
            const int col = nt * 16 + row16;
            const int sw = (q4 << 4) ^ ((col & 3) << 4);
            f32x4 p0 = *reinterpret_cast<f32x4*>(&sm[(0 * 2 + r) * 8192 + col * 64 + sw]);
            f32x4 p1 = *reinterpret_cast<f32x4*>(&sm[(1 * 2 + r) * 8192 + col * 64 + sw]);
            f32x4 p2 = *reinterpret_cast<f32x4*>(&sm[(2 * 2 + r) * 8192 + col * 64 + sw]);
            #pragma unroll
            for (int e = 0; e < 4; ++e) {
                float vv = (acc[nt][e] + p0[e] + p1[e] + p2[e]) * linv[e];
                vv = (vv > 0.f) ? vv : expm1f(vv);
                out[(size_t)(b * NN + rg * 32 + r * 16 + (q4 << 2) + e) * NF + col] = vv;
            }
        }
    }
}

extern "C" void kernel_launch(void* const* d_in, const int* in_sizes, int n_in,
                              void* d_out, int out_size, void* d_ws, size_t ws_size,
                              hipStream_t stream) {
    (void)in_sizes; (void)n_in; (void)out_size; (void)ws_size;
    const float* h      = (const float*)d_in[0];
    const int*   adj    = (const int*)d_in[1];
    const float* dist   = (const float*)d_in[2];
    const float* W      = (const float*)d_in[3];
    const float* a      = (const float*)d_in[4];
    const float* scaler = (const float*)d_in[5];
    float* out = (float*)d_out;

    char* ws = (char*)d_ws;
    unsigned short* hpT = (unsigned short*)ws;                 // 4 MiB
    float* siC   = (float*)(ws + 4 * 1024 * 1024);             // 64 KiB
    float* sjC   = (float*)(ws + 4 * 1024 * 1024 + 65536);     // 64 KiB
    float* biasC = (float*)(ws + 4 * 1024 * 1024 + 2 * 65536); // 16 MiB

    k_hprime<<<dim3(NB * NN / 64), dim3(256), 0, stream>>>(h, W, a, hpT, siC, sjC);
    k_bias<<<dim3(NN * NN / 1024), dim3(256), 0, stream>>>(adj, dist, scaler, biasC);
    k_attn<<<dim3(NB * NN / 32), dim3(512), 0, stream>>>(hpT, siC, sjC, biasC, out);
}